// Round 1
// baseline (713.281 us; speedup 1.0000x reference)
//
#include <hip/hip_runtime.h>
#include <hip/hip_bf16.h>

#define BB   8
#define CC   80
#define HH   128
#define WW   128
#define HWN  16384
#define KTOP 100
#define NCAND 2048   // max candidates per (b,c) map (provable bound 1849 + slack)
#define NSTG2 8192   // next pow2 >= C*KTOP = 8000

__device__ __forceinline__ float sigmoidf_(float x) {
    // mirror jax.nn.sigmoid numerics (branch on sign)
    if (x >= 0.0f) return 1.0f / (1.0f + expf(-x));
    float e = expf(x);
    return e / (1.0f + e);
}

// ---------------- Kernel A: sigmoid + 5x5 peak NMS + per-map top-100 ----------------
__global__ __launch_bounds__(256) void kmap(const float* __restrict__ cls_logits,
                                            unsigned long long* __restrict__ s1keys) {
    __shared__ float s[HWN];                    // 64KB sigmoid map
    __shared__ unsigned long long cand[NCAND];  // 16KB candidate keys
    __shared__ int cnt;

    const int map = blockIdx.x;                 // b*C + c
    const float* __restrict__ src = cls_logits + (size_t)map * HWN;
    const int tid = threadIdx.x;
    if (tid == 0) cnt = 0;

    for (int i = tid; i < HWN; i += 256) {
        s[i] = sigmoidf_(src[i]);
    }
    __syncthreads();

    for (int i = tid; i < HWN; i += 256) {
        const int h = i >> 7, w = i & 127;
        const float v = s[i];
        float m = v;
        const int h0 = max(h - 2, 0), h1 = min(h + 2, HH - 1);
        const int w0 = max(w - 2, 0), w1 = min(w + 2, WW - 1);
        for (int hh = h0; hh <= h1; ++hh) {
            const float* row = s + hh * WW;
            for (int ww = w0; ww <= w1; ++ww)
                m = fmaxf(m, row[ww]);
        }
        if (v == m) {  // keep: equals 5x5 window max of sigmoid (matches hmax==cls)
            int slot = atomicAdd(&cnt, 1);
            if (slot < NCAND) {
                unsigned long long vb = (unsigned long long)__float_as_uint(v);
                // key: value desc primary, hw asc secondary (via complement)
                cand[slot] = (vb << 14) | (unsigned long long)(16383 - i);
            }
        }
    }
    __syncthreads();

    const int n = min(cnt, NCAND);
    for (int i = tid; i < NCAND; i += 256)
        if (i >= n) cand[i] = 0ULL;
    __syncthreads();

    // bitonic sort descending over NCAND keys
    for (int k = 2; k <= NCAND; k <<= 1) {
        for (int j = k >> 1; j > 0; j >>= 1) {
            for (int i = tid; i < NCAND; i += 256) {
                const int ixj = i ^ j;
                if (ixj > i) {
                    unsigned long long a = cand[i], b = cand[ixj];
                    const bool desc = ((i & k) == 0);
                    if (desc ? (a < b) : (a > b)) { cand[i] = b; cand[ixj] = a; }
                }
            }
            __syncthreads();
        }
    }

    for (int r = tid; r < KTOP; r += 256)
        s1keys[(size_t)map * KTOP + r] = cand[r];
}

// ---------------- Kernel B: per-batch global top-100 over C*KTOP entries ----------------
__global__ __launch_bounds__(1024) void ktop(const unsigned long long* __restrict__ s1keys,
                                             float* __restrict__ out,
                                             int* __restrict__ sel) {
    __shared__ unsigned long long arr[NSTG2];   // 64KB
    const int b = blockIdx.x, tid = threadIdx.x;

    for (int i = tid; i < NSTG2; i += 1024) {
        unsigned long long key = 0ULL;
        if (i < CC * KTOP) {
            unsigned long long kin = s1keys[(size_t)b * CC * KTOP + i];
            unsigned long long vb = kin >> 14;
            unsigned long long hw = 16383ULL - (kin & 0x3FFFULL);
            // value desc primary, entry-index asc secondary, hw payload
            key = (vb << 27) | ((unsigned long long)(NSTG2 - 1 - i) << 14) | hw;
        }
        arr[i] = key;
    }
    __syncthreads();

    for (int k = 2; k <= NSTG2; k <<= 1) {
        for (int j = k >> 1; j > 0; j >>= 1) {
            for (int i = tid; i < NSTG2; i += 1024) {
                const int ixj = i ^ j;
                if (ixj > i) {
                    unsigned long long a = arr[i], bv = arr[ixj];
                    const bool desc = ((i & k) == 0);
                    if (desc ? (a < bv) : (a > bv)) { arr[i] = bv; arr[ixj] = a; }
                }
            }
            __syncthreads();
        }
    }

    for (int r = tid; r < KTOP; r += 1024) {
        const unsigned long long key = arr[r];
        const int hw = (int)(key & 0x3FFFULL);
        const int entry = (NSTG2 - 1) - (int)((key >> 14) & 0x1FFFULL);
        const float sc = __uint_as_float((unsigned int)(key >> 27));
        const int cls = entry / KTOP;
        // out layout (all float32): score[0..800) | bbox[800..4000) | inds[4000..4800) | clses[4800..5600)
        out[b * KTOP + r]            = sc;
        out[4000 + b * KTOP + r]     = (float)hw;
        out[4800 + b * KTOP + r]     = (float)cls;
        sel[b * KTOP + r]            = hw;
    }
}

// ---------------- Kernel C: decode boxes at the 800 selected locations ----------------
__global__ __launch_bounds__(256) void kdecode(const float* __restrict__ txty,
                                               const float* __restrict__ twth,
                                               const int* __restrict__ sel,
                                               float* __restrict__ out) {
    const int i = blockIdx.x * blockDim.x + threadIdx.x;
    if (i >= BB * KTOP) return;
    const int b = i / KTOP;
    const int hw = sel[i];
    const int xx = hw & 127, yy = hw >> 7;

    const float* __restrict__ t = txty + (size_t)b * 2 * HWN;
    const float* __restrict__ u = twth + (size_t)b * 2 * HWN;
    const float tx = t[hw], ty = t[HWN + hw];
    const float tw = u[hw], th = u[HWN + hw];

    const float cx = (sigmoidf_(tx) + (float)xx) * 4.0f;
    const float cy = (sigmoidf_(ty) + (float)yy) * 4.0f;
    const float bw = expf(tw) * 4.0f;
    const float bh = expf(th) * 4.0f;

    const float inv = 1.0f / 512.0f;
    float x1 = (cx - bw * 0.5f) * inv;
    float y1 = (cy - bh * 0.5f) * inv;
    float x2 = (cx + bw * 0.5f) * inv;
    float y2 = (cy + bh * 0.5f) * inv;
    x1 = fminf(fmaxf(x1, 0.0f), 1.0f);
    y1 = fminf(fmaxf(y1, 0.0f), 1.0f);
    x2 = fminf(fmaxf(x2, 0.0f), 1.0f);
    y2 = fminf(fmaxf(y2, 0.0f), 1.0f);

    float* bb = out + 800 + (size_t)i * 4;
    bb[0] = x1; bb[1] = y1; bb[2] = x2; bb[3] = y2;
}

extern "C" void kernel_launch(void* const* d_in, const int* in_sizes, int n_in,
                              void* d_out, int out_size, void* d_ws, size_t ws_size,
                              hipStream_t stream) {
    const float* cls_logits = (const float*)d_in[0];
    const float* txty       = (const float*)d_in[1];
    const float* twth       = (const float*)d_in[2];
    float* out = (float*)d_out;

    unsigned long long* s1keys = (unsigned long long*)d_ws;            // B*C*KTOP = 64000 keys (512KB)
    int* sel = (int*)((char*)d_ws + (size_t)BB * CC * KTOP * 8);       // 800 ints

    kmap<<<BB * CC, 256, 0, stream>>>(cls_logits, s1keys);
    ktop<<<BB, 1024, 0, stream>>>(s1keys, out, sel);
    kdecode<<<(BB * KTOP + 255) / 256, 256, 0, stream>>>(txty, twth, sel, out);
}

// Round 3
// 151.709 us; speedup vs baseline: 4.7016x; 4.7016x over previous
//
#include <hip/hip_runtime.h>
#include <hip/hip_bf16.h>

#define BB   8
#define CC   80
#define HH   128
#define WW   128
#define HWN  16384
#define KTOP 100
#define SR   32          // rows per strip
#define LR   (SR + 4)    // strip rows + 2-row halo each side
#define SCAP 512         // per-strip candidate capacity (theoretical ~473, data ~165)

__device__ __forceinline__ float sigmoidf_(float x) {
    // mirror jax.nn.sigmoid numerics (branch on sign) — bitwise-matched in R1
    if (x >= 0.0f) return 1.0f / (1.0f + expf(-x));
    float e = expf(x);
    return e / (1.0f + e);
}

// Global lexicographic key: value desc, class asc, hw asc (53 bits).
// Equivalent to the reference's two-stage top-k ordering:
//  - any filtered (non-class-top-100) entry lex-ahead of a selected entry X
//    implies >=100 surviving same-class entries lex-ahead of X -> contradiction.
__device__ __forceinline__ unsigned long long makekey(float v, int cls, int hw) {
    return ((unsigned long long)__float_as_uint(v) << 21)
         | ((unsigned long long)(127 - cls) << 14)
         | (unsigned long long)(16383 - hw);
}

#define BITONIC_DESC(arr, N2, NTHR)                                         \
    for (int k_ = 2; k_ <= (N2); k_ <<= 1) {                                \
        for (int j_ = k_ >> 1; j_ > 0; j_ >>= 1) {                          \
            for (int i_ = threadIdx.x; i_ < (N2); i_ += (NTHR)) {           \
                const int ixj_ = i_ ^ j_;                                   \
                if (ixj_ > i_) {                                            \
                    unsigned long long a_ = (arr)[i_], b_ = (arr)[ixj_];    \
                    if (((i_ & k_) == 0) ? (a_ < b_) : (a_ > b_)) {         \
                        (arr)[i_] = b_; (arr)[ixj_] = a_;                   \
                    }                                                       \
                }                                                           \
            }                                                               \
            __syncthreads();                                                \
        }                                                                   \
    }

// ---- Kernel A: sigmoid + separable 5x5 peak NMS per 32-row strip + strip top-100 ----
__global__ __launch_bounds__(256, 4) void knms(const float* __restrict__ cls_logits,
                                               unsigned long long* __restrict__ strips1) {
    __shared__ float s[LR][WW];                  // 18432 B sigmoid tile (with halo)
    __shared__ float vm[SR][WW];                 // 16384 B vertical 5-max
    __shared__ unsigned long long cand[SCAP];    // 4096 B
    __shared__ int cnt;

    const int tid   = threadIdx.x;
    const int map   = blockIdx.x >> 2;           // b*CC + c
    const int strip = blockIdx.x & 3;
    const int cls   = map % CC;
    const int R0    = strip * SR;
    const float* __restrict__ src = cls_logits + (size_t)map * HWN;
    if (tid == 0) cnt = 0;

    // load + sigmoid, float4 vectorized; halo rows clamped to map edges
    for (int v = tid; v < LR * (WW / 4); v += 256) {
        const int lr = v >> 5;
        const int c4 = (v & 31) << 2;
        int gr = R0 - 2 + lr;
        gr = gr < 0 ? 0 : (gr > HH - 1 ? HH - 1 : gr);
        const float4 f = *reinterpret_cast<const float4*>(src + (size_t)gr * WW + c4);
        s[lr][c4 + 0] = sigmoidf_(f.x);
        s[lr][c4 + 1] = sigmoidf_(f.y);
        s[lr][c4 + 2] = sigmoidf_(f.z);
        s[lr][c4 + 3] = sigmoidf_(f.w);
    }
    __syncthreads();

    // vertical 5-max (clamped halo rows duplicate edge rows == -inf-pad window max)
    for (int i = tid; i < SR * WW; i += 256) {
        const int r = i >> 7, c = i & 127;
        float m = fmaxf(fmaxf(s[r][c], s[r + 1][c]), fmaxf(s[r + 2][c], s[r + 3][c]));
        vm[r][c] = fmaxf(m, s[r + 4][c]);
    }
    __syncthreads();

    // horizontal 5-max (clamped duplicate reads) + keep + block compact
    for (int i = tid; i < SR * WW; i += 256) {
        const int r = i >> 7, c = i & 127;
        const int cm2 = c - 2 < 0 ? 0 : c - 2;
        const int cm1 = c - 1 < 0 ? 0 : c - 1;
        const int cp1 = c + 1 > 127 ? 127 : c + 1;
        const int cp2 = c + 2 > 127 ? 127 : c + 2;
        float m = fmaxf(fmaxf(vm[r][cm2], vm[r][cm1]), fmaxf(vm[r][c], vm[r][cp1]));
        m = fmaxf(m, vm[r][cp2]);
        const float v = s[r + 2][c];
        if (v == m) {
            const int slot = atomicAdd(&cnt, 1);
            if (slot < SCAP) cand[slot] = makekey(v, cls, ((R0 + r) << 7) | c);
        }
    }
    __syncthreads();

    int n = cnt < SCAP ? cnt : SCAP;
    int n2 = 128;                                 // >= KTOP
    while (n2 < n) n2 <<= 1;
    for (int i = tid; i < n2; i += 256) if (i >= n) cand[i] = 0ULL;
    __syncthreads();

    BITONIC_DESC(cand, n2, 256);

    for (int r = tid; r < KTOP; r += 256)
        strips1[(size_t)blockIdx.x * KTOP + r] = cand[r];
}

// ---- Kernel B: per-map merge of 4 strip top-100s -> per-map top-100 ----
__global__ __launch_bounds__(256) void kmerge(const unsigned long long* __restrict__ strips1,
                                              unsigned long long* __restrict__ s1) {
    __shared__ unsigned long long a[512];
    const int tid = threadIdx.x, map = blockIdx.x;
    for (int i = tid; i < 512; i += 256)
        a[i] = (i < 4 * KTOP) ? strips1[(size_t)map * 4 * KTOP + i] : 0ULL;
    __syncthreads();
    BITONIC_DESC(a, 512, 256);
    for (int r = tid; r < KTOP; r += 256)
        s1[(size_t)map * KTOP + r] = a[r];
}

// ---- Kernel C1: per (batch, 10-map group): 1000 -> top-100.  8 groups/batch ----
__global__ __launch_bounds__(256) void kgroup(const unsigned long long* __restrict__ s1,
                                              unsigned long long* __restrict__ g1) {
    __shared__ unsigned long long a[1024];
    const int tid = threadIdx.x, blk = blockIdx.x;   // blk = b*8 + g, maps [blk*10, blk*10+10)
    for (int i = tid; i < 1024; i += 256)
        a[i] = (i < 1000) ? s1[(size_t)blk * 1000 + i] : 0ULL;
    __syncthreads();
    BITONIC_DESC(a, 1024, 256);
    for (int r = tid; r < KTOP; r += 256)
        g1[(size_t)blk * KTOP + r] = a[r];
}

// ---- Kernel C2: per batch: 8*100 -> top-100, write outputs + fused box decode ----
__global__ __launch_bounds__(256) void kfinal(const unsigned long long* __restrict__ g1,
                                              const float* __restrict__ txty,
                                              const float* __restrict__ twth,
                                              float* __restrict__ out) {
    __shared__ unsigned long long a[1024];
    const int tid = threadIdx.x, b = blockIdx.x;
    for (int i = tid; i < 1024; i += 256)
        a[i] = (i < 8 * KTOP) ? g1[(size_t)b * 8 * KTOP + i] : 0ULL;
    __syncthreads();
    BITONIC_DESC(a, 1024, 256);

    if (tid < KTOP) {
        const unsigned long long key = a[tid];
        const int hw  = 16383 - (int)(key & 0x3FFFULL);
        const int cls = 127 - (int)((key >> 14) & 0x7FULL);
        const float sc = __uint_as_float((unsigned int)(key >> 21));

        // out layout (float32): score[0..800) | bbox[800..4000) | inds[4000..4800) | clses[4800..5600)
        out[b * KTOP + tid]        = sc;
        out[4000 + b * KTOP + tid] = (float)hw;
        out[4800 + b * KTOP + tid] = (float)cls;

        const int xx = hw & 127, yy = hw >> 7;
        const float* __restrict__ t = txty + (size_t)b * 2 * HWN;
        const float* __restrict__ u = twth + (size_t)b * 2 * HWN;
        const float tx = t[hw], ty = t[HWN + hw];
        const float tw = u[hw], th = u[HWN + hw];

        const float cx = (sigmoidf_(tx) + (float)xx) * 4.0f;
        const float cy = (sigmoidf_(ty) + (float)yy) * 4.0f;
        const float bw = expf(tw) * 4.0f;
        const float bh = expf(th) * 4.0f;

        const float inv = 1.0f / 512.0f;
        float x1 = (cx - bw * 0.5f) * inv;
        float y1 = (cy - bh * 0.5f) * inv;
        float x2 = (cx + bw * 0.5f) * inv;
        float y2 = (cy + bh * 0.5f) * inv;
        x1 = fminf(fmaxf(x1, 0.0f), 1.0f);
        y1 = fminf(fmaxf(y1, 0.0f), 1.0f);
        x2 = fminf(fmaxf(x2, 0.0f), 1.0f);
        y2 = fminf(fmaxf(y2, 0.0f), 1.0f);

        float* bb = out + 800 + (size_t)(b * KTOP + tid) * 4;
        bb[0] = x1; bb[1] = y1; bb[2] = x2; bb[3] = y2;
    }
}

extern "C" void kernel_launch(void* const* d_in, const int* in_sizes, int n_in,
                              void* d_out, int out_size, void* d_ws, size_t ws_size,
                              hipStream_t stream) {
    const float* cls_logits = (const float*)d_in[0];
    const float* txty       = (const float*)d_in[1];
    const float* twth       = (const float*)d_in[2];
    float* out = (float*)d_out;

    // ws layout (bytes):
    //   strips1: 2560 * 100 * 8 = 2,048,000
    //   s1:       640 * 100 * 8 =   512,000
    //   g1:        64 * 100 * 8 =    51,200
    unsigned long long* strips1 = (unsigned long long*)d_ws;
    unsigned long long* s1 = (unsigned long long*)((char*)d_ws + 2048000);
    unsigned long long* g1 = (unsigned long long*)((char*)d_ws + 2048000 + 512000);

    knms  <<<BB * CC * 4, 256, 0, stream>>>(cls_logits, strips1);
    kmerge<<<BB * CC,     256, 0, stream>>>(strips1, s1);
    kgroup<<<BB * 8,      256, 0, stream>>>(s1, g1);
    kfinal<<<BB,          256, 0, stream>>>(g1, txty, twth, out);
}

// Round 4
// 65.950 us; speedup vs baseline: 10.8155x; 2.3004x over previous
//
#include <hip/hip_runtime.h>
#include <hip/hip_bf16.h>

#define BB   8
#define CC   80
#define HH   128
#define WW   128
#define HWN  16384
#define KTOP 100
#define NSTRIP 8         // strips per map
#define SR   16          // rows per strip
#define LR   (SR + 4)    // strip rows + 2-row halo each side
#define SCAP 512         // per-strip candidate cap (theoretical ~258, data ~82)

typedef unsigned long long ull;

__device__ __forceinline__ float sigmoidf_(float x) {
    // bitwise-matched vs jax.nn.sigmoid in R1/R3
    if (x >= 0.0f) return 1.0f / (1.0f + expf(-x));
    float e = expf(x);
    return e / (1.0f + e);
}

// Lexicographic key: value desc, class asc, hw asc. Unique per (map,hw).
// Global ordering by this key == reference two-stage top-k ordering (proof R2/R3).
__device__ __forceinline__ ull makekey(float v, int cls, int hw) {
    return ((ull)__float_as_uint(v) << 21)
         | ((ull)(127 - cls) << 14)
         | (ull)(16383 - hw);
}

#define BITONIC_DESC(arr, N2, NTHR)                                         \
    for (int k_ = 2; k_ <= (N2); k_ <<= 1) {                                \
        for (int j_ = k_ >> 1; j_ > 0; j_ >>= 1) {                          \
            for (int i_ = threadIdx.x; i_ < (N2); i_ += (NTHR)) {           \
                const int ixj_ = i_ ^ j_;                                   \
                if (ixj_ > i_) {                                            \
                    ull a_ = (arr)[i_], b_ = (arr)[ixj_];                   \
                    if (((i_ & k_) == 0) ? (a_ < b_) : (a_ > b_)) {         \
                        (arr)[i_] = b_; (arr)[ixj_] = a_;                   \
                    }                                                       \
                }                                                           \
            }                                                               \
            __syncthreads();                                                \
        }                                                                   \
    }

// Tournament of sorted desc 128-chunks (zero-padded tails).
// Each round merges chunk p with chunk p+newn, keeping the top-128 (sorted)
// in chunk p: 1 valley-halving stage + 7 desc bitonic-merge stages.
__device__ __forceinline__ void merge_rounds(ull (*ch)[128], int nch, int NT) {
    const int tid = threadIdx.x;
    while (nch > 1) {
        const int newn  = (nch + 1) >> 1;
        const int npair = nch - newn;
        // valley halving: [A desc ; rev(B)] bitonic -> max-half into A (bitonic)
        for (int t = tid; t < npair * 128; t += NT) {
            const int p = t >> 7, i = t & 127;
            ull a = ch[p][i], b = ch[p + newn][127 - i];
            if (a < b) { ch[p][i] = b; ch[p + newn][127 - i] = a; }
        }
        __syncthreads();
        // desc bitonic merge of each winner chunk
        for (int j = 64; j >= 1; j >>= 1) {
            for (int t = tid; t < npair * 64; t += NT) {
                const int p = t >> 6, q = t & 63;
                const int i = ((q & ~(j - 1)) << 1) | (q & (j - 1));
                ull a = ch[p][i], b = ch[p][i | j];
                if (a < b) { ch[p][i] = b; ch[p][i | j] = a; }
            }
            __syncthreads();
        }
        nch = newn;
    }
}

// ---- Kernel A: sigmoid + separable 5x5 peak NMS per 16-row strip + strip top-100 ----
__global__ __launch_bounds__(256) void knms(const float* __restrict__ cls_logits,
                                            ull* __restrict__ strips1) {
    __shared__ float s[LR][WW];      // 10240 B
    __shared__ float vm[SR][WW];     // 8192 B
    __shared__ ull cand[SCAP];       // 4096 B
    __shared__ int cnt;

    const int tid   = threadIdx.x;
    const int map   = blockIdx.x >> 3;          // b*CC + c
    const int strip = blockIdx.x & 7;
    const int cls   = map % CC;
    const int R0    = strip * SR;
    const float* __restrict__ src = cls_logits + (size_t)map * HWN;
    if (tid == 0) cnt = 0;

    for (int v = tid; v < LR * (WW / 4); v += 256) {
        const int lr = v >> 5;
        const int c4 = (v & 31) << 2;
        int gr = R0 - 2 + lr;
        gr = gr < 0 ? 0 : (gr > HH - 1 ? HH - 1 : gr);
        const float4 f = *reinterpret_cast<const float4*>(src + (size_t)gr * WW + c4);
        s[lr][c4 + 0] = sigmoidf_(f.x);
        s[lr][c4 + 1] = sigmoidf_(f.y);
        s[lr][c4 + 2] = sigmoidf_(f.z);
        s[lr][c4 + 3] = sigmoidf_(f.w);
    }
    __syncthreads();

    // vertical 5-max (clamped halo rows duplicate edges == -inf padding)
    for (int i = tid; i < SR * WW; i += 256) {
        const int r = i >> 7, c = i & 127;
        float m = fmaxf(fmaxf(s[r][c], s[r + 1][c]), fmaxf(s[r + 2][c], s[r + 3][c]));
        vm[r][c] = fmaxf(m, s[r + 4][c]);
    }
    __syncthreads();

    // horizontal 5-max + keep + compact
    for (int i = tid; i < SR * WW; i += 256) {
        const int r = i >> 7, c = i & 127;
        const int cm2 = c - 2 < 0 ? 0 : c - 2;
        const int cm1 = c - 1 < 0 ? 0 : c - 1;
        const int cp1 = c + 1 > 127 ? 127 : c + 1;
        const int cp2 = c + 2 > 127 ? 127 : c + 2;
        float m = fmaxf(fmaxf(vm[r][cm2], vm[r][cm1]), fmaxf(vm[r][c], vm[r][cp1]));
        m = fmaxf(m, vm[r][cp2]);
        const float v = s[r + 2][c];
        if (v == m) {
            const int slot = atomicAdd(&cnt, 1);
            if (slot < SCAP) cand[slot] = makekey(v, cls, ((R0 + r) << 7) | c);
        }
    }
    __syncthreads();

    const int n = cnt < SCAP ? cnt : SCAP;
    int n2 = 128;
    while (n2 < n) n2 <<= 1;
    for (int i = tid; i < n2; i += 256) if (i >= n) cand[i] = 0ULL;
    __syncthreads();

    BITONIC_DESC(cand, n2, 256);

    for (int r = tid; r < KTOP; r += 256)
        strips1[(size_t)blockIdx.x * KTOP + r] = cand[r];
}

// ---- Kernel B: per-map tournament of 8 sorted strip lists -> map top-100 ----
__global__ __launch_bounds__(256) void kmerge(const ull* __restrict__ strips1,
                                              ull* __restrict__ s1) {
    __shared__ ull ch[NSTRIP][128];
    const int tid = threadIdx.x, map = blockIdx.x;
    for (int t = tid; t < NSTRIP * 128; t += 256) {
        const int p = t >> 7, i = t & 127;
        ch[p][i] = (i < KTOP) ? strips1[((size_t)map * NSTRIP + p) * KTOP + i] : 0ULL;
    }
    __syncthreads();
    merge_rounds(ch, NSTRIP, 256);
    for (int r = tid; r < KTOP; r += 256)
        s1[(size_t)map * KTOP + r] = ch[0][r];
}

// ---- Kernel C1: per (batch,10-map group) tournament -> group top-100 ----
__global__ __launch_bounds__(256) void kgrp(const ull* __restrict__ s1,
                                            ull* __restrict__ g1) {
    __shared__ ull ch[10][128];
    const int tid = threadIdx.x, blk = blockIdx.x;   // maps [blk*10, blk*10+10)
    for (int t = tid; t < 10 * 128; t += 256) {
        const int p = t / 128, i = t & 127;
        ch[p][i] = (i < KTOP) ? s1[((size_t)blk * 10 + p) * KTOP + i] : 0ULL;
    }
    __syncthreads();
    merge_rounds(ch, 10, 256);
    for (int r = tid; r < KTOP; r += 256)
        g1[(size_t)blk * KTOP + r] = ch[0][r];
}

// ---- Kernel C2: per batch tournament of 8 group lists -> top-100 + decode ----
__global__ __launch_bounds__(256) void kfin(const ull* __restrict__ g1,
                                            const float* __restrict__ txty,
                                            const float* __restrict__ twth,
                                            float* __restrict__ out) {
    __shared__ ull ch[8][128];
    const int tid = threadIdx.x, b = blockIdx.x;
    for (int t = tid; t < 8 * 128; t += 256) {
        const int p = t >> 7, i = t & 127;
        ch[p][i] = (i < KTOP) ? g1[((size_t)b * 8 + p) * KTOP + i] : 0ULL;
    }
    __syncthreads();
    merge_rounds(ch, 8, 256);

    if (tid < KTOP) {
        const ull key = ch[0][tid];
        const int hw  = 16383 - (int)(key & 0x3FFFULL);
        const int cls = 127 - (int)((key >> 14) & 0x7FULL);
        const float sc = __uint_as_float((unsigned int)(key >> 21));

        // out layout (float32): score[0..800) | bbox[800..4000) | inds[4000..4800) | clses[4800..5600)
        out[b * KTOP + tid]        = sc;
        out[4000 + b * KTOP + tid] = (float)hw;
        out[4800 + b * KTOP + tid] = (float)cls;

        const int xx = hw & 127, yy = hw >> 7;
        const float* __restrict__ t = txty + (size_t)b * 2 * HWN;
        const float* __restrict__ u = twth + (size_t)b * 2 * HWN;
        const float tx = t[hw], ty = t[HWN + hw];
        const float tw = u[hw], th = u[HWN + hw];

        const float cx = (sigmoidf_(tx) + (float)xx) * 4.0f;
        const float cy = (sigmoidf_(ty) + (float)yy) * 4.0f;
        const float bw = expf(tw) * 4.0f;
        const float bh = expf(th) * 4.0f;

        const float inv = 1.0f / 512.0f;
        float x1 = (cx - bw * 0.5f) * inv;
        float y1 = (cy - bh * 0.5f) * inv;
        float x2 = (cx + bw * 0.5f) * inv;
        float y2 = (cy + bh * 0.5f) * inv;
        x1 = fminf(fmaxf(x1, 0.0f), 1.0f);
        y1 = fminf(fmaxf(y1, 0.0f), 1.0f);
        x2 = fminf(fmaxf(x2, 0.0f), 1.0f);
        y2 = fminf(fmaxf(y2, 0.0f), 1.0f);

        float* bb = out + 800 + (size_t)(b * KTOP + tid) * 4;
        bb[0] = x1; bb[1] = y1; bb[2] = x2; bb[3] = y2;
    }
}

extern "C" void kernel_launch(void* const* d_in, const int* in_sizes, int n_in,
                              void* d_out, int out_size, void* d_ws, size_t ws_size,
                              hipStream_t stream) {
    const float* cls_logits = (const float*)d_in[0];
    const float* txty       = (const float*)d_in[1];
    const float* twth       = (const float*)d_in[2];
    float* out = (float*)d_out;

    // ws layout (bytes):
    //   strips1: 5120 * 100 * 8 = 4,096,000
    //   s1:       640 * 100 * 8 =   512,000   @ 4,096,000
    //   g1:        64 * 100 * 8 =    51,200   @ 4,608,000
    ull* strips1 = (ull*)d_ws;
    ull* s1 = (ull*)((char*)d_ws + 4096000);
    ull* g1 = (ull*)((char*)d_ws + 4608000);

    knms  <<<BB * CC * NSTRIP, 256, 0, stream>>>(cls_logits, strips1);
    kmerge<<<BB * CC,          256, 0, stream>>>(strips1, s1);
    kgrp  <<<64,               256, 0, stream>>>(s1, g1);
    kfin  <<<BB,               256, 0, stream>>>(g1, txty, twth, out);
}